// Round 6
// baseline (1230.750 us; speedup 1.0000x reference)
//
#include <hip/hip_runtime.h>
#include <hip/hip_bf16.h>
#include <cstdint>
#include <cstddef>

// ---- problem constants ----
#define CD    1152          // hidden
#define NTOK  4096
#define MTOK  300
#define BSZ   2
#define HID2  5760          // 2*HID
#define HIDD  2880          // HID
#define ROWS  (BSZ*NTOK)    // 8192
#define KVROWS (BSZ*MTOK)   // 600

using bf16 = __hip_bfloat16;
typedef __bf16 bf16x8 __attribute__((ext_vector_type(8)));
typedef __bf16 bf16x4 __attribute__((ext_vector_type(4)));
typedef float f32x4 __attribute__((ext_vector_type(4)));

__device__ __forceinline__ float b2f(bf16 h) { return __bfloat162float(h); }
__device__ __forceinline__ bf16  f2b(float f) { return __float2bfloat16(f); }
__device__ __forceinline__ bf16x8 bz8() {
    bf16x8 v;
    #pragma unroll
    for (int j = 0; j < 8; ++j) v[j] = (__bf16)0.0f;
    return v;
}

// async global->LDS, 16B per lane; lds base must be wave-uniform (HW writes
// base + lane*16) [m97 / m104]
__device__ __forceinline__ void gload16(const void* g, void* l) {
    __builtin_amdgcn_global_load_lds(
        (const __attribute__((address_space(1))) void*)g,
        (__attribute__((address_space(3))) void*)l, 16, 0, 0);
}

// ---------------- fused prep ----------------
// qkv_w and inv_w are written in PACKED MFMA-B-fragment order for gemm_as:
//   Wp[((n16*KC + kc)*64 + lane)*8 + j] = W[n16*16 + (lane&15)][kc*32 + (lane>>4)*8 + j]
// Other weights stay row-major bf16 (used by gemm_bt).
#define PB0 497664    // qkv_w packed   3981312 elems
#define PB1 663552    // aproj_w
#define PB2 829440    // q_w
#define PB3 1161216   // kv_w
#define PB4 1327104   // cproj_w
#define PB5 2156544   // inv_w packed  +6635520
#define PB6 2571264   // pw_w
#define PB7 2657664   // y
#define PB8 2659392   // mod
#define PB9 2665872   // dww
#define PB10 2675376  // vk zero

__device__ __forceinline__ void cast8(const float* __restrict__ s, bf16* __restrict__ d, int i) {
    f32x4 a = *(const f32x4*)&s[i];
    f32x4 b = *(const f32x4*)&s[i + 4];
    bf16x8 o;
    #pragma unroll
    for (int j = 0; j < 4; ++j) { o[j] = (__bf16)a[j]; o[4 + j] = (__bf16)b[j]; }
    *(bf16x8*)&d[i] = o;
}

// pack one vec8 unit u of W (Nout x K, K=1152, KC=36) into fragment order
__device__ __forceinline__ void pack8(const float* __restrict__ w, bf16* __restrict__ d, int u) {
    const int l = u & 63;
    const int rest = u >> 6;
    const int kc = rest % 36;
    const int n16 = rest / 36;
    const float* src = &w[(size_t)(n16 * 16 + (l & 15)) * CD + kc * 32 + (l >> 4) * 8];
    f32x4 a = *(const f32x4*)src;
    f32x4 b = *(const f32x4*)(src + 4);
    bf16x8 o;
    #pragma unroll
    for (int j = 0; j < 4; ++j) { o[j] = (__bf16)a[j]; o[4 + j] = (__bf16)b[j]; }
    *(bf16x8*)&d[u * 8] = o;
}

__global__ __launch_bounds__(256) void prep_all(
    const float* __restrict__ qkv_w, const float* __restrict__ aproj_w,
    const float* __restrict__ q_w, const float* __restrict__ kv_w,
    const float* __restrict__ cproj_w, const float* __restrict__ inv_w,
    const float* __restrict__ pw_w, const float* __restrict__ y,
    const float* __restrict__ sst, const float* __restrict__ tt,
    const float* __restrict__ dww,
    bf16* __restrict__ wqkv, bf16* __restrict__ waproj, bf16* __restrict__ wq,
    bf16* __restrict__ wkv, bf16* __restrict__ wcproj, bf16* __restrict__ winv,
    bf16* __restrict__ wpw, bf16* __restrict__ yb, float* __restrict__ mbuf,
    bf16* __restrict__ wtdw, float* __restrict__ vkbuf) {
    const int u = blockIdx.x * 256 + threadIdx.x;
    if (u < PB0)      pack8(qkv_w, wqkv, u);                  // packed for gemm_as
    else if (u < PB1) cast8(aproj_w, waproj, (u - PB0) * 8);
    else if (u < PB2) cast8(q_w,     wq,     (u - PB1) * 8);
    else if (u < PB3) cast8(kv_w,    wkv,    (u - PB2) * 8);
    else if (u < PB4) cast8(cproj_w, wcproj, (u - PB3) * 8);
    else if (u < PB5) pack8(inv_w,   winv,   u - PB4);        // packed for gemm_as
    else if (u < PB6) cast8(pw_w,    wpw,    (u - PB5) * 8);
    else if (u < PB7) cast8(y,       yb,     (u - PB6) * 8);
    else if (u < PB8) {
        const int i = (u - PB7) * 8;
        const int si = (i < 6 * CD) ? i : i - 6 * CD;
        #pragma unroll
        for (int c = 0; c < 2; ++c) {
            f32x4 a = *(const f32x4*)&tt[i + c * 4];
            f32x4 s = *(const f32x4*)&sst[si + c * 4];
            f32x4 o;
            #pragma unroll
            for (int j = 0; j < 4; ++j) o[j] = a[j] + s[j];
            *(f32x4*)&mbuf[i + c * 4] = o;
        }
    } else if (u < PB9) {
        const int i = (u - PB8) * 8;
        const int k = i / HID2, c = i - k * HID2;
        bf16x8 o;
        #pragma unroll
        for (int j = 0; j < 8; ++j) o[j] = (__bf16)dww[(c + j) * 9 + k];
        *(bf16x8*)&wtdw[i] = o;
    } else if (u < PB10) {
        const int i = (u - PB9) * 8;
        f32x4 z = {};
        *(f32x4*)&vkbuf[i] = z;
        *(f32x4*)&vkbuf[i + 4] = z;
    }
}

// LayerNorm (no affine) + adaLN modulation: out = norm(x)*(1+sc)+sh, bf16 out
__global__ __launch_bounds__(256) void ln_mod(
    const float* __restrict__ xf, const float* __restrict__ m,
    int shRow, int scRow, bf16* __restrict__ out) {
    const int row = blockIdx.x, tid = threadIdx.x;
    const int b = row >> 12;            // rowsPerBatch = 4096
    const f32x4* xr = (const f32x4*)(xf + (size_t)row * CD);
    f32x4 v0 = xr[tid];
    f32x4 v1 = {};
    if (tid < 32) v1 = xr[256 + tid];
    float s = 0.f, s2 = 0.f;
    #pragma unroll
    for (int j = 0; j < 4; ++j) {
        s += v0[j] + v1[j];
        s2 += v0[j] * v0[j] + v1[j] * v1[j];
    }
    #pragma unroll
    for (int off = 32; off; off >>= 1) {
        s  += __shfl_down(s,  off, 64);
        s2 += __shfl_down(s2, off, 64);
    }
    __shared__ float red[8];
    const int wid = tid >> 6, lane = tid & 63;
    if (lane == 0) { red[wid] = s; red[4 + wid] = s2; }
    __syncthreads();
    s  = red[0] + red[1] + red[2] + red[3];
    s2 = red[4] + red[5] + red[6] + red[7];
    const float mu  = s / CD;
    const float var = s2 / CD - mu * mu;
    const float rs  = rsqrtf(var + 1e-6f);
    const f32x4* shp = (const f32x4*)&m[((size_t)b * 6 + shRow) * CD];
    const f32x4* scp = (const f32x4*)&m[((size_t)b * 6 + scRow) * CD];
    bf16x4* ob = (bf16x4*)(out + (size_t)row * CD);
    {
        f32x4 sh = shp[tid], sc = scp[tid];
        bf16x4 o;
        #pragma unroll
        for (int j = 0; j < 4; ++j) o[j] = (__bf16)((v0[j] - mu) * rs * (1.f + sc[j]) + sh[j]);
        ob[tid] = o;
    }
    if (tid < 32) {
        f32x4 sh = shp[256 + tid], sc = scp[256 + tid];
        bf16x4 o;
        #pragma unroll
        for (int j = 0; j < 4; ++j) o[j] = (__bf16)((v1[j] - mu) * rs * (1.f + sc[j]) + sh[j]);
        ob[256 + tid] = o;
    }
}

// ---------------- A-stationary barrier-free GEMM (K=1152 shapes) ----------------
// Block = 512 thr (8 waves). A-panel (64 rows x K) staged to LDS once; then each
// wave independently streams 64-col tiles: K-loop has NO barriers — only
// compiler-inserted vmcnt/lgkmcnt between packed-W loads, A ds_reads and MFMA.
// EPI 1: relu if col<reluCols -> bf16 (qkv); EPI 2: silu(+bias) -> bf16 (inv)
template<int EPI>
__global__ __launch_bounds__(512) void gemm_as(
    const bf16* __restrict__ A, const bf16* __restrict__ Wp,
    const float* __restrict__ bias, bf16* __restrict__ outb,
    int K, int Nout, int reluCols, int colStreams) {
    __shared__ bf16 Apan[64 * 1160];      // row stride 1160: 2-way banks (free)
    const int tid = threadIdx.x;
    const int row0 = blockIdx.x * 64;
    const int KC = K >> 5;
    const int vec8PerRow = K >> 3;
    for (int i = tid; i < 64 * vec8PerRow; i += 512) {
        const int r = i / vec8PerRow, c8 = i - r * vec8PerRow;
        *(bf16x8*)&Apan[r * 1160 + c8 * 8] =
            *(const bf16x8*)&A[(size_t)(row0 + r) * K + c8 * 8];
    }
    __syncthreads();   // the only barrier

    const int wid = tid >> 6, lane = tid & 63;
    const int l16 = lane & 15, l4 = lane >> 4;
    const int TN = Nout >> 6;
    for (int t = blockIdx.y * 8 + wid; t < TN; t += colStreams) {
        f32x4 acc[4][4] = {};
        const bf16* wpt = Wp + (size_t)(4 * t) * KC * 512;
        #pragma unroll 4
        for (int kc = 0; kc < KC; ++kc) {
            bf16x8 b[4], a[4];
            #pragma unroll
            for (int j = 0; j < 4; ++j)
                b[j] = *(const bf16x8*)&wpt[(size_t)(j * KC + kc) * 512 + lane * 8];
            #pragma unroll
            for (int i = 0; i < 4; ++i)
                a[i] = *(const bf16x8*)&Apan[(i * 16 + l16) * 1160 + kc * 32 + l4 * 8];
            #pragma unroll
            for (int i = 0; i < 4; ++i)
                #pragma unroll
                for (int j = 0; j < 4; ++j)
                    acc[i][j] = __builtin_amdgcn_mfma_f32_16x16x32_bf16(a[i], b[j], acc[i][j], 0, 0, 0);
        }
        #pragma unroll
        for (int j = 0; j < 4; ++j) {
            const int gc = t * 64 + j * 16 + l16;
            const float bv = (EPI == 2) ? bias[gc] : 0.f;
            #pragma unroll
            for (int i = 0; i < 4; ++i) {
                #pragma unroll
                for (int r = 0; r < 4; ++r) {
                    float v = acc[i][j][r];
                    if (EPI == 1) { if (gc < reluCols) v = fmaxf(v, 0.f); }
                    else { v += bv; v = v / (1.f + __expf(-v)); }
                    outb[(size_t)(row0 + i * 16 + l4 * 4 + r) * Nout + gc] = f2b(v);
                }
            }
        }
    }
}

// ---------------- bf16 MFMA GEMM (m97-style, remaining shapes) ----------------
// EPI 0: +bias -> bf16 ; EPI 3: resf+gate*(+bias) -> f32+bf16 (aproj)
// EPI 4: resf+(+bias) -> f32 (cproj) ; EPI 5: resf+gate*acc -> f32 (pw)
template<int EPI>
__global__ __launch_bounds__(256) void gemm_bt(
    const bf16* __restrict__ A, const bf16* __restrict__ W,
    const float* __restrict__ bias, const float* __restrict__ resf,
    const float* __restrict__ gate, int gateStride,
    bf16* __restrict__ outb, float* __restrict__ outf,
    int rows, int K, int Nout, int reluCols, int nRowB, int nColB) {
    __shared__ __align__(16) char smem[33792];
    bf16* As = (bf16*)smem;             // [128][64]
    bf16* Bs = (bf16*)(smem + 16384);   // [128][64]
    const int bid = blockIdx.x;
    int row_blk = bid % nRowB, col_blk = bid / nRowB;
    const int row0 = row_blk * 128;
    const int col0 = col_blk * 128;
    const int tid = threadIdx.x;
    const int wid = tid >> 6, lane = tid & 63;
    const int wm = wid & 1, wn = wid >> 1;
    const int l16 = lane & 15, l4 = lane >> 4;
    f32x4 acc[4][4] = {};

    const int sr = tid >> 3;
    const int kbsw = (((tid & 7) ^ (sr & 7)) << 3);
    int gra[4], gcl[4];
    #pragma unroll
    for (int p = 0; p < 4; ++p) {
        int r = row0 + p * 32 + sr; if (r >= rows) r = rows - 1;
        gra[p] = r;
        gcl[p] = col0 + p * 32 + sr;
    }
    char* AsB = smem + wid * 1024;
    char* BsB = smem + 16384 + wid * 1024;

    for (int k0 = 0; k0 < K; k0 += 64) {
        __syncthreads();
        #pragma unroll
        for (int p = 0; p < 4; ++p) {
            gload16(&A[(size_t)gra[p] * K + k0 + kbsw], AsB + p * 4096);
            gload16(&W[(size_t)gcl[p] * K + k0 + kbsw], BsB + p * 4096);
        }
        __syncthreads();
        #pragma unroll
        for (int kk = 0; kk < 2; ++kk) {
            bf16x8 a[4], b[4];
            #pragma unroll
            for (int i = 0; i < 4; ++i) {
                const int ar = wm * 64 + i * 16 + l16;
                a[i] = *(const bf16x8*)&As[ar * 64 + ((((kk << 2) + l4) ^ (ar & 7)) << 3)];
            }
            #pragma unroll
            for (int j = 0; j < 4; ++j) {
                const int br = wn * 64 + j * 16 + l16;
                b[j] = *(const bf16x8*)&Bs[br * 64 + ((((kk << 2) + l4) ^ (br & 7)) << 3)];
            }
            #pragma unroll
            for (int i = 0; i < 4; ++i)
                #pragma unroll
                for (int j = 0; j < 4; ++j)
                    acc[i][j] = __builtin_amdgcn_mfma_f32_16x16x32_bf16(a[i], b[j], acc[i][j], 0, 0, 0);
        }
    }

    float* Lf = (float*)smem;               // [64][130]
    const int erow = tid >> 4;
    const int ecol = (tid & 15) * 8;
    const int gc = col0 + ecol;
    #pragma unroll
    for (int pass = 0; pass < 2; ++pass) {
        __syncthreads();
        if (wm == pass) {
            #pragma unroll
            for (int i = 0; i < 4; ++i)
                #pragma unroll
                for (int j = 0; j < 4; ++j) {
                    const int lc = wn * 64 + j * 16 + l16;
                    #pragma unroll
                    for (int r = 0; r < 4; ++r)
                        Lf[(i * 16 + l4 * 4 + r) * 130 + lc] = acc[i][j][r];
                }
        }
        __syncthreads();
        #pragma unroll
        for (int rr = 0; rr < 4; ++rr) {
            const int lrow = rr * 16 + erow;
            const int gr = row0 + pass * 64 + lrow;
            if (gr >= rows) continue;
            float v[8];
            #pragma unroll
            for (int c = 0; c < 8; ++c) v[c] = Lf[lrow * 130 + ecol + c];
            const size_t oi0 = (size_t)gr * Nout + gc;
            if (EPI == 0) {
                bf16x8 ob;
                #pragma unroll
                for (int c = 0; c < 8; ++c) ob[c] = (__bf16)(v[c] + bias[gc + c]);
                *(bf16x8*)&outb[oi0] = ob;
            } else if (EPI == 3) {
                const float* gp = &gate[(gr >> 12) * gateStride + gc];
                const float* rp = &resf[oi0];
                f32x4 o0, o1; bf16x8 ob;
                #pragma unroll
                for (int c = 0; c < 8; ++c) {
                    float t = v[c] + bias[gc + c];
                    t = rp[c] + gp[c] * t;
                    if (c < 4) o0[c] = t; else o1[c - 4] = t;
                    ob[c] = (__bf16)t;
                }
                *(f32x4*)&outf[oi0] = o0;
                *(f32x4*)&outf[oi0 + 4] = o1;
                *(bf16x8*)&outb[oi0] = ob;
            } else if (EPI == 4) {
                const float* rp = &resf[oi0];
                f32x4 o0, o1;
                #pragma unroll
                for (int c = 0; c < 8; ++c) {
                    float t = rp[c] + v[c] + bias[gc + c];
                    if (c < 4) o0[c] = t; else o1[c - 4] = t;
                }
                *(f32x4*)&outf[oi0] = o0;
                *(f32x4*)&outf[oi0 + 4] = o1;
            } else {   // EPI 5
                const float* gp = &gate[(gr >> 12) * gateStride + gc];
                const float* rp = &resf[oi0];
                f32x4 o0, o1;
                #pragma unroll
                for (int c = 0; c < 8; ++c) {
                    float t = rp[c] + gp[c] * v[c];
                    if (c < 4) o0[c] = t; else o1[c - 4] = t;
                }
                *(f32x4*)&outf[oi0] = o0;
                *(f32x4*)&outf[oi0 + 4] = o1;
            }
        }
    }
}

// ---------------- LiteLA: vk = [v;1] @ k^T over n, per (b,h) ----------------
__global__ __launch_bounds__(256) void lite_vk(
    const bf16* __restrict__ qkv, float* __restrict__ vk) {
    const int b = blockIdx.x / 36, h = blockIdx.x % 36;
    const int n0 = blockIdx.y * 256;
    __shared__ bf16 ksm[64 * 32];
    __shared__ bf16 vsm[64 * 32];
    const int t = threadIdx.x;
    const int ev = t >> 3, kq = (t & 7) * 4;
    float a0 = 0, a1 = 0, a2 = 0, a3 = 0;
    float q0 = 0, q1 = 0, q2 = 0, q3 = 0;
    for (int tile = 0; tile < 4; ++tile) {
        const int nb = n0 + tile * 64;
        __syncthreads();
        {
            const int nl = t >> 2, part = (t & 3) * 8;
            const size_t rbase = ((size_t)b * NTOK + nb + nl) * (3 * CD);
            *(bf16x8*)&ksm[nl * 32 + part] = *(const bf16x8*)&qkv[rbase + CD     + h * 32 + part];
            *(bf16x8*)&vsm[nl * 32 + part] = *(const bf16x8*)&qkv[rbase + 2 * CD + h * 32 + part];
        }
        __syncthreads();
        #pragma unroll 4
        for (int nl = 0; nl < 64; ++nl) {
            const float vv = b2f(vsm[nl * 32 + ev]);
            const float k0 = b2f(ksm[nl * 32 + kq + 0]);
            const float k1 = b2f(ksm[nl * 32 + kq + 1]);
            const float k2 = b2f(ksm[nl * 32 + kq + 2]);
            const float k3 = b2f(ksm[nl * 32 + kq + 3]);
            a0 += vv * k0; a1 += vv * k1; a2 += vv * k2; a3 += vv * k3;
            if (ev == 0) { q0 += k0; q1 += k1; q2 += k2; q3 += k3; }
        }
    }
    float* dst = &vk[(((size_t)b * 36 + h) * 33 + ev) * 32 + kq];
    atomicAdd(dst + 0, a0); atomicAdd(dst + 1, a1);
    atomicAdd(dst + 2, a2); atomicAdd(dst + 3, a3);
    if (ev == 0) {
        float* d2 = &vk[(((size_t)b * 36 + h) * 33 + 32) * 32 + kq];
        atomicAdd(d2 + 0, q0); atomicAdd(d2 + 1, q1);
        atomicAdd(d2 + 2, q2); atomicAdd(d2 + 3, q3);
    }
}

// u[b,n,h*32+d] = (vk[d,:] . q) / (vk[32,:] . q + eps)
__global__ __launch_bounds__(256) void lite_out(
    const bf16* __restrict__ qkv, const float* __restrict__ vk,
    bf16* __restrict__ u) {
    const int b = blockIdx.x / 36, h = blockIdx.x % 36;
    const int n = blockIdx.y * 256 + threadIdx.x;
    __shared__ float vks[33 * 32];
    const float* src = &vk[((size_t)b * 36 + h) * 33 * 32];
    for (int i = threadIdx.x; i < 33 * 32; i += 256) vks[i] = src[i];
    __syncthreads();
    float q[32];
    const bf16x8* qv = (const bf16x8*)&qkv[((size_t)b * NTOK + n) * (3 * CD) + h * 32];
    #pragma unroll
    for (int w = 0; w < 4; ++w) {
        bf16x8 qq = qv[w];
        #pragma unroll
        for (int e = 0; e < 8; ++e) q[w * 8 + e] = (float)qq[e];
    }
    float denom = 0.f;
    #pragma unroll
    for (int e = 0; e < 32; ++e) denom += vks[32 * 32 + e] * q[e];
    const float rd = 1.f / (denom + 1e-8f);
    bf16* up = &u[((size_t)b * NTOK + n) * CD + h * 32];
    #pragma unroll 1
    for (int d = 0; d < 32; ++d) {
        float acc = 0.f;
        #pragma unroll
        for (int e = 0; e < 32; ++e) acc += vks[d * 32 + e] * q[e];
        up[d] = f2b(acc * rd);
    }
}

// ---------------- cross attention prep: K zero-pad + V transpose ----------------
__global__ __launch_bounds__(256) void prep_attn(
    const bf16* __restrict__ kvb, bf16* __restrict__ Kp, bf16* __restrict__ VtG) {
    const int b = blockIdx.x >> 4, h = blockIdx.x & 15;
    const int tid = threadIdx.x;
    bf16* kp = Kp + (size_t)blockIdx.x * (320 * 72);
    bf16* vt = VtG + (size_t)blockIdx.x * (80 * 328);
    const bf16x8 z = bz8();
    for (int i = tid; i < 320 * 9; i += 256) {
        const int m = i / 9, part = (i % 9) * 8;
        bf16x8 v = z;
        if (m < MTOK)
            v = *(const bf16x8*)&kvb[((size_t)b * MTOK + m) * (2 * CD) + h * 72 + part];
        *(bf16x8*)&kp[m * 72 + part] = v;
    }
    for (int i = tid; i < 80 * 328; i += 256) {
        const int d = i / 328, mm = i - d * 328;
        bf16 v = f2b(0.f);
        if (mm < MTOK && d < 72)
            v = kvb[((size_t)b * MTOK + mm) * (2 * CD) + CD + h * 72 + d];
        vt[i] = v;
    }
}

// ---------------- cross attention: MFMA flash, 64 Q-rows per block ----------------
__global__ __launch_bounds__(256) void cross_attn_mfma(
    const bf16* __restrict__ qx, const bf16* __restrict__ Kp,
    const bf16* __restrict__ VtG, bf16* __restrict__ attn) {
    const int bh = blockIdx.x;
    const int b = bh >> 4;
    const int row0 = blockIdx.y * 64;
    __shared__ bf16 Ks[320 * 72];
    __shared__ bf16 Vt[80 * 328];
    __shared__ bf16 Ps[64 * 328];
    const int tid = threadIdx.x;
    const int wid = tid >> 6, lane = tid & 63;
    const int l16 = lane & 15, l4 = lane >> 4;
    const bf16 zb = f2b(0.f);
    const bf16x8 zv8 = bz8();

    {
        const bf16x8* Kg = (const bf16x8*)(Kp + (size_t)bh * (320 * 72));
        bf16x8* Kl = (bf16x8*)Ks;
        for (int i = tid; i < 2880; i += 256) Kl[i] = Kg[i];
        const bf16x8* Vg = (const bf16x8*)(VtG + (size_t)bh * (80 * 328));
        bf16x8* Vl = (bf16x8*)Vt;
        for (int i = tid; i < 3280; i += 256) Vl[i] = Vg[i];
    }
    for (int i = lane; i < 16 * 16; i += 64)
        Ps[(wid * 16 + (i >> 4)) * 328 + 304 + (i & 15)] = zb;

    bf16x8 aq[3];
    {
        const int qrow = row0 + wid * 16 + l16;
        const bf16* qp = &qx[((size_t)b * NTOK + qrow) * CD + (bh & 15) * 72];
        aq[0] = *(const bf16x8*)&qp[l4 * 8];
        aq[1] = *(const bf16x8*)&qp[32 + l4 * 8];
        aq[2] = (l4 == 0) ? *(const bf16x8*)&qp[64] : zv8;
    }
    __syncthreads();

    f32x4 sa[19] = {};
    #pragma unroll
    for (int t = 0; t < 19; ++t) {
        const bf16* kr = &Ks[(t * 16 + l16) * 72];
        bf16x8 b0 = *(const bf16x8*)&kr[l4 * 8];
        bf16x8 b1 = *(const bf16x8*)&kr[32 + l4 * 8];
        bf16x8 b2 = (l4 == 0) ? *(const bf16x8*)&kr[64] : zv8;
        sa[t] = __builtin_amdgcn_mfma_f32_16x16x32_bf16(aq[0], b0, sa[t], 0, 0, 0);
        sa[t] = __builtin_amdgcn_mfma_f32_16x16x32_bf16(aq[1], b1, sa[t], 0, 0, 0);
        sa[t] = __builtin_amdgcn_mfma_f32_16x16x32_bf16(aq[2], b2, sa[t], 0, 0, 0);
    }

    const float scale = 0.11785113019775792f;   // 1/sqrt(72)
    if (l16 >= 12) { sa[18][0] = sa[18][1] = sa[18][2] = sa[18][3] = -3.0e37f; }
    float mr[4] = {-3.0e38f, -3.0e38f, -3.0e38f, -3.0e38f};
    #pragma unroll
    for (int t = 0; t < 19; ++t)
        #pragma unroll
        for (int r = 0; r < 4; ++r) {
            const float s = sa[t][r] * scale;
            sa[t][r] = s;
            mr[r] = fmaxf(mr[r], s);
        }
    #pragma unroll
    for (int off = 1; off < 16; off <<= 1)
        #pragma unroll
        for (int r = 0; r < 4; ++r)
            mr[r] = fmaxf(mr[r], __shfl_xor(mr[r], off, 64));
    float lr[4] = {0.f, 0.f, 0.f, 0.f};
    #pragma unroll
    for (int t = 0; t < 19; ++t)
        #pragma unroll
        for (int r = 0; r < 4; ++r) {
            const float p = __expf(sa[t][r] - mr[r]);
            lr[r] += p;
            Ps[(wid * 16 + l4 * 4 + r) * 328 + t * 16 + l16] = f2b(p);
        }
    #pragma unroll
    for (int off = 1; off < 16; off <<= 1)
        #pragma unroll
        for (int r = 0; r < 4; ++r)
            lr[r] += __shfl_xor(lr[r], off, 64);
    __syncthreads();

    f32x4 oa[5] = {};
    #pragma unroll
    for (int kc = 0; kc < 10; ++kc) {
        bf16x8 pa = *(const bf16x8*)&Ps[(wid * 16 + l16) * 328 + kc * 32 + l4 * 8];
        #pragma unroll
        for (int dt = 0; dt < 5; ++dt) {
            bf16x8 vb = *(const bf16x8*)&Vt[(dt * 16 + l16) * 328 + kc * 32 + l4 * 8];
            oa[dt] = __builtin_amdgcn_mfma_f32_16x16x32_bf16(pa, vb, oa[dt], 0, 0, 0);
        }
    }
    #pragma unroll
    for (int r = 0; r < 4; ++r) {
        const float rinv = 1.f / lr[r];
        const int gr = row0 + wid * 16 + l4 * 4 + r;
        bf16* op = &attn[((size_t)b * NTOK + gr) * CD + (bh & 15) * 72];
        #pragma unroll
        for (int dt = 0; dt < 5; ++dt) {
            const int d = dt * 16 + l16;
            if (d < 72) op[d] = f2b(oa[dt][r] * rinv);
        }
    }
}

// ---------------- depthwise 3x3 conv + GLU (8 ch/thread, 16B loads) ----------------
__global__ __launch_bounds__(128) void dwconv_glu2(
    const bf16* __restrict__ hbuf, const bf16* __restrict__ wt,
    const float* __restrict__ dwb, bf16* __restrict__ glu) {
    const int cg = blockIdx.y * 128 + threadIdx.x;
    if (cg >= 360) return;
    const int c0 = cg * 8;
    const int n = blockIdx.x & 4095;
    const int b = blockIdx.x >> 12;
    const int y0 = n >> 6, x0 = n & 63;
    float a[8], g[8];
    #pragma unroll
    for (int j = 0; j < 8; ++j) { a[j] = dwb[c0 + j]; g[j] = dwb[HIDD + c0 + j]; }
    #pragma unroll
    for (int dy = -1; dy <= 1; ++dy) {
        const int yy = y0 + dy;
        if (yy < 0 || yy >= 64) continue;
        #pragma unroll
        for (int dx = -1; dx <= 1; ++dx) {
            const int xx = x0 + dx;
            if (xx < 0 || xx >= 64) continue;
            const int k = (dy + 1) * 3 + (dx + 1);
            const size_t base = ((size_t)b * NTOK + yy * 64 + xx) * HID2;
            const bf16x8 va = *(const bf16x8*)&hbuf[base + c0];
            const bf16x8 vg = *(const bf16x8*)&hbuf[base + HIDD + c0];
            const bf16x8 wa = *(const bf16x8*)&wt[k * HID2 + c0];
            const bf16x8 wg = *(const bf16x8*)&wt[k * HID2 + HIDD + c0];
            #pragma unroll
            for (int j = 0; j < 8; ++j) {
                a[j] += (float)wa[j] * (float)va[j];
                g[j] += (float)wg[j] * (float)vg[j];
            }
        }
    }
    bf16x8 o;
    #pragma unroll
    for (int j = 0; j < 8; ++j) {
        const float s = g[j] / (1.f + __expf(-g[j]));
        o[j] = (__bf16)(a[j] * s);
    }
    *(bf16x8*)&glu[((size_t)b * NTOK + n) * HIDD + c0] = o;
}

// ---------------- launcher ----------------
extern "C" void kernel_launch(void* const* d_in, const int* in_sizes, int n_in,
                              void* d_out, int out_size, void* d_ws, size_t ws_size,
                              hipStream_t stream) {
    (void)in_sizes; (void)n_in; (void)out_size; (void)ws_size;
    const float* x       = (const float*)d_in[0];
    const float* y       = (const float*)d_in[1];
    const float* t       = (const float*)d_in[2];
    const float* sst     = (const float*)d_in[3];
    const float* qkv_w   = (const float*)d_in[4];
    const float* aproj_w = (const float*)d_in[5];
    const float* aproj_b = (const float*)d_in[6];
    const float* q_w     = (const float*)d_in[7];
    const float* q_b     = (const float*)d_in[8];
    const float* kv_w    = (const float*)d_in[9];
    const float* kv_b    = (const float*)d_in[10];
    const float* cproj_w = (const float*)d_in[11];
    const float* cproj_b = (const float*)d_in[12];
    const float* inv_w   = (const float*)d_in[13];
    const float* inv_b   = (const float*)d_in[14];
    const float* dw_w    = (const float*)d_in[15];
    const float* dw_b    = (const float*)d_in[16];
    const float* pw_w    = (const float*)d_in[17];
    float* out = (float*)d_out;

    char* ws = (char*)d_ws;
    size_t cur = 0;
    auto take = [&](size_t bytes) -> char* {
        char* p = ws + cur;
        cur = (cur + bytes + 255) & ~(size_t)255;
        return p;
    };
    float* mbuf   = (float*)take(BSZ * 6 * CD * 4);
    float* vkbuf  = (float*)take(BSZ * 36 * 33 * 32 * 4);
    bf16* wqkv    = (bf16*)take((size_t)3 * CD * CD * 2);   // PACKED
    bf16* waproj  = (bf16*)take((size_t)CD * CD * 2);
    bf16* wq      = (bf16*)take((size_t)CD * CD * 2);
    bf16* wkv     = (bf16*)take((size_t)2 * CD * CD * 2);
    bf16* wcproj  = (bf16*)take((size_t)CD * CD * 2);
    bf16* winv    = (bf16*)take((size_t)HID2 * CD * 2);     // PACKED
    bf16* wpw     = (bf16*)take((size_t)CD * HIDD * 2);
    bf16* wtdw    = (bf16*)take((size_t)9 * HID2 * 2);
    bf16* yb      = (bf16*)take((size_t)KVROWS * CD * 2);
    bf16* kvbuf   = (bf16*)take((size_t)KVROWS * 2 * CD * 2);
    bf16* Kp      = (bf16*)take((size_t)32 * 320 * 72 * 2);
    bf16* VtG     = (bf16*)take((size_t)32 * 80 * 328 * 2);
    bf16* P       = (bf16*)take((size_t)ROWS * HID2 * 2);   // qkv, later h
    bf16* Q       = (bf16*)take((size_t)ROWS * HIDD * 2);   // u, later glu
    bf16* R       = (bf16*)take((size_t)ROWS * CD * 2);     // x1 / xa_bf / attn / x2
    bf16* S       = (bf16*)take((size_t)ROWS * CD * 2);     // qx
    float* xa_f   = (float*)take((size_t)ROWS * CD * 4);

    bf16* qkvb = P;  bf16* hbuf = P;
    bf16* ubuf = Q;  bf16* glub = Q;
    bf16* x1 = R, *xa_bf = R, *attnb = R, *x2 = R;
    bf16* qx = S;
    float* xb_f = out;  // d_out doubles as the f32 xb buffer

    prep_all<<<(PB10 + 255) / 256, 256, 0, stream>>>(
        qkv_w, aproj_w, q_w, kv_w, cproj_w, inv_w, pw_w, y, sst, t, dw_w,
        wqkv, waproj, wq, wkv, wcproj, winv, wpw, yb, mbuf, wtdw, vkbuf);

    // --- LiteLA branch ---
    ln_mod<<<ROWS, 256, 0, stream>>>(x, mbuf, 0, 1, x1);
    gemm_as<1><<<dim3(128, 2), 512, 0, stream>>>(x1, wqkv, nullptr, qkvb,
                                                 CD, 3 * CD, 2 * CD, 16);
    lite_vk<<<dim3(72, 16), 256, 0, stream>>>(qkvb, vkbuf);
    lite_out<<<dim3(72, 16), 256, 0, stream>>>(qkvb, vkbuf, ubuf);
    gemm_bt<3><<<64 * 9, 256, 0, stream>>>(ubuf, waproj, aproj_b, x, mbuf + 2 * CD, 6 * CD,
                                           xa_bf, xa_f, ROWS, CD, CD, 0, 64, 9);

    // --- cross attention branch ---
    gemm_bt<0><<<64 * 9, 256, 0, stream>>>(xa_bf, wq, q_b, nullptr, nullptr, 0,
                                           qx, nullptr, ROWS, CD, CD, 0, 64, 9);
    gemm_bt<0><<<5 * 18, 256, 0, stream>>>(yb, wkv, kv_b, nullptr, nullptr, 0,
                                           kvbuf, nullptr, KVROWS, CD, 2 * CD, 0, 5, 18);
    prep_attn<<<32, 256, 0, stream>>>(kvbuf, Kp, VtG);
    cross_attn_mfma<<<dim3(32, 64), 256, 0, stream>>>(qx, Kp, VtG, attnb);
    gemm_bt<4><<<64 * 9, 256, 0, stream>>>(attnb, wcproj, cproj_b, xa_f, nullptr, 0,
                                           nullptr, xb_f, ROWS, CD, CD, 0, 64, 9);

    // --- GLUMBConv branch ---
    ln_mod<<<ROWS, 256, 0, stream>>>(xb_f, mbuf, 3, 4, x2);
    gemm_as<2><<<dim3(128, 2), 512, 0, stream>>>(x2, winv, inv_b, hbuf,
                                                 CD, HID2, 0, 16);
    dwconv_glu2<<<dim3(ROWS, 3), 128, 0, stream>>>(hbuf, wtdw, dw_b, glub);
    gemm_bt<5><<<64 * 9, 256, 0, stream>>>(glub, wpw, nullptr, xb_f, mbuf + 5 * CD, 6 * CD,
                                           nullptr, out, ROWS, HIDD, CD, 0, 64, 9);
}

// Round 8
// 976.488 us; speedup vs baseline: 1.2604x; 1.2604x over previous
//
#include <hip/hip_runtime.h>
#include <hip/hip_bf16.h>
#include <cstdint>
#include <cstddef>

// ---- problem constants ----
#define CD    1152          // hidden
#define NTOK  4096
#define MTOK  300
#define BSZ   2
#define HID2  5760          // 2*HID
#define HIDD  2880          // HID
#define ROWS  (BSZ*NTOK)    // 8192
#define KVROWS (BSZ*MTOK)   // 600

#define WSC   64.0f         // fp8 weight pre-scale
#define WSCI  (1.0f/64.0f)

using bf16 = __hip_bfloat16;
typedef __bf16 bf16x8 __attribute__((ext_vector_type(8)));
typedef __bf16 bf16x4 __attribute__((ext_vector_type(4)));
typedef float f32x4 __attribute__((ext_vector_type(4)));

__device__ __forceinline__ float b2f(bf16 h) { return __bfloat162float(h); }
__device__ __forceinline__ bf16  f2b(float f) { return __float2bfloat16(f); }
__device__ __forceinline__ bf16x8 bz8() {
    bf16x8 v;
    #pragma unroll
    for (int j = 0; j < 8; ++j) v[j] = (__bf16)0.0f;
    return v;
}

// HW fp8 pack: v_cvt_pk_fp8_f32 (gfx950 -> OCP e4m3, same format the fp8 MFMA reads)
__device__ __forceinline__ uint32_t pk4f8(float f0, float f1, float f2, float f3) {
    int v = 0;
    v = __builtin_amdgcn_cvt_pk_fp8_f32(f0, f1, v, false);   // bytes 0,1
    v = __builtin_amdgcn_cvt_pk_fp8_f32(f2, f3, v, true);    // bytes 2,3
    return (uint32_t)v;
}

// async global->LDS, 16B per lane; lds base must be wave-uniform (HW writes
// base + lane*16) [m97 / m104]
__device__ __forceinline__ void gload16(const void* g, void* l) {
    __builtin_amdgcn_global_load_lds(
        (const __attribute__((address_space(1))) void*)g,
        (__attribute__((address_space(3))) void*)l, 16, 0, 0);
}

// ---------------- fused prep ----------------
// qkv_w and inv_w cast to fp8 e4m3 (x64 scale), row-major, for gemm_f8.
// segment boundaries in vec8 units
#define PB0 497664    // qkv_w fp8
#define PB1 663552    // aproj_w
#define PB2 829440    // q_w
#define PB3 1161216   // kv_w
#define PB4 1327104   // cproj_w
#define PB5 2156544   // inv_w fp8
#define PB6 2571264   // pw_w
#define PB7 2657664   // y
#define PB8 2659392   // mod
#define PB9 2665872   // dww
#define PB10 2675376  // vk zero

__device__ __forceinline__ void cast8(const float* __restrict__ s, bf16* __restrict__ d, int i) {
    f32x4 a = *(const f32x4*)&s[i];
    f32x4 b = *(const f32x4*)&s[i + 4];
    bf16x8 o;
    #pragma unroll
    for (int j = 0; j < 4; ++j) { o[j] = (__bf16)a[j]; o[4 + j] = (__bf16)b[j]; }
    *(bf16x8*)&d[i] = o;
}

__device__ __forceinline__ void cast8f8(const float* __restrict__ s, uint8_t* __restrict__ d, int i) {
    f32x4 a = *(const f32x4*)&s[i];
    f32x4 b = *(const f32x4*)&s[i + 4];
    uint32_t lo = pk4f8(a[0] * WSC, a[1] * WSC, a[2] * WSC, a[3] * WSC);
    uint32_t hi = pk4f8(b[0] * WSC, b[1] * WSC, b[2] * WSC, b[3] * WSC);
    *(uint32_t*)&d[i] = lo;
    *(uint32_t*)&d[i + 4] = hi;
}

__global__ __launch_bounds__(256) void prep_all(
    const float* __restrict__ qkv_w, const float* __restrict__ aproj_w,
    const float* __restrict__ q_w, const float* __restrict__ kv_w,
    const float* __restrict__ cproj_w, const float* __restrict__ inv_w,
    const float* __restrict__ pw_w, const float* __restrict__ y,
    const float* __restrict__ sst, const float* __restrict__ tt,
    const float* __restrict__ dww,
    uint8_t* __restrict__ wqkv, bf16* __restrict__ waproj, bf16* __restrict__ wq,
    bf16* __restrict__ wkv, bf16* __restrict__ wcproj, uint8_t* __restrict__ winv,
    bf16* __restrict__ wpw, bf16* __restrict__ yb, float* __restrict__ mbuf,
    bf16* __restrict__ wtdw, float* __restrict__ vkbuf) {
    const int u = blockIdx.x * 256 + threadIdx.x;
    if (u < PB0)      cast8f8(qkv_w, wqkv, u * 8);
    else if (u < PB1) cast8(aproj_w, waproj, (u - PB0) * 8);
    else if (u < PB2) cast8(q_w,     wq,     (u - PB1) * 8);
    else if (u < PB3) cast8(kv_w,    wkv,    (u - PB2) * 8);
    else if (u < PB4) cast8(cproj_w, wcproj, (u - PB3) * 8);
    else if (u < PB5) cast8f8(inv_w, winv,   (u - PB4) * 8);
    else if (u < PB6) cast8(pw_w,    wpw,    (u - PB5) * 8);
    else if (u < PB7) cast8(y,       yb,     (u - PB6) * 8);
    else if (u < PB8) {
        const int i = (u - PB7) * 8;
        const int si = (i < 6 * CD) ? i : i - 6 * CD;
        #pragma unroll
        for (int c = 0; c < 2; ++c) {
            f32x4 a = *(const f32x4*)&tt[i + c * 4];
            f32x4 s = *(const f32x4*)&sst[si + c * 4];
            f32x4 o;
            #pragma unroll
            for (int j = 0; j < 4; ++j) o[j] = a[j] + s[j];
            *(f32x4*)&mbuf[i + c * 4] = o;
        }
    } else if (u < PB9) {
        const int i = (u - PB8) * 8;
        const int k = i / HID2, c = i - k * HID2;
        bf16x8 o;
        #pragma unroll
        for (int j = 0; j < 8; ++j) o[j] = (__bf16)dww[(c + j) * 9 + k];
        *(bf16x8*)&wtdw[i] = o;
    } else if (u < PB10) {
        const int i = (u - PB9) * 8;
        f32x4 z = {};
        *(f32x4*)&vkbuf[i] = z;
        *(f32x4*)&vkbuf[i + 4] = z;
    }
}

// LayerNorm + adaLN modulation -> fp8 e4m3 output (feeds gemm_f8)
__global__ __launch_bounds__(256) void ln_mod8(
    const float* __restrict__ xf, const float* __restrict__ m,
    int shRow, int scRow, uint8_t* __restrict__ out) {
    const int row = blockIdx.x, tid = threadIdx.x;
    const int b = row >> 12;
    const f32x4* xr = (const f32x4*)(xf + (size_t)row * CD);
    f32x4 v0 = xr[tid];
    f32x4 v1 = {};
    if (tid < 32) v1 = xr[256 + tid];
    float s = 0.f, s2 = 0.f;
    #pragma unroll
    for (int j = 0; j < 4; ++j) {
        s += v0[j] + v1[j];
        s2 += v0[j] * v0[j] + v1[j] * v1[j];
    }
    #pragma unroll
    for (int off = 32; off; off >>= 1) {
        s  += __shfl_down(s,  off, 64);
        s2 += __shfl_down(s2, off, 64);
    }
    __shared__ float red[8];
    const int wid = tid >> 6, lane = tid & 63;
    if (lane == 0) { red[wid] = s; red[4 + wid] = s2; }
    __syncthreads();
    s  = red[0] + red[1] + red[2] + red[3];
    s2 = red[4] + red[5] + red[6] + red[7];
    const float mu  = s / CD;
    const float var = s2 / CD - mu * mu;
    const float rs  = rsqrtf(var + 1e-6f);
    const f32x4* shp = (const f32x4*)&m[((size_t)b * 6 + shRow) * CD];
    const f32x4* scp = (const f32x4*)&m[((size_t)b * 6 + scRow) * CD];
    uint32_t* ob = (uint32_t*)(out + (size_t)row * CD);
    {
        f32x4 sh = shp[tid], sc = scp[tid];
        float w[4];
        #pragma unroll
        for (int j = 0; j < 4; ++j) w[j] = (v0[j] - mu) * rs * (1.f + sc[j]) + sh[j];
        ob[tid] = pk4f8(w[0], w[1], w[2], w[3]);
    }
    if (tid < 32) {
        f32x4 sh = shp[256 + tid], sc = scp[256 + tid];
        float w[4];
        #pragma unroll
        for (int j = 0; j < 4; ++j) w[j] = (v1[j] - mu) * rs * (1.f + sc[j]) + sh[j];
        ob[256 + tid] = pk4f8(w[0], w[1], w[2], w[3]);
    }
}

// ---------------- fp8 MFMA GEMM: out = A(rows,K) @ W(Nout,K)^T, f32 accum ----------------
// A, W in fp8 e4m3 (W pre-scaled x64). BK=64: 16 KB staged/iter (half of bf16)
// -> 131 FLOP per staged byte. 16B-unit XOR swizzle; ds_read_b64 fragments.
// EPI 1: (acc/64), relu if col<reluCols -> bf16 (qkv)
// EPI 2: silu(acc/64 + bias) -> bf16 (inv)
template<int EPI>
__global__ __launch_bounds__(256) void gemm_f8(
    const uint8_t* __restrict__ A, const uint8_t* __restrict__ W,
    const float* __restrict__ bias, bf16* __restrict__ outb,
    int rows, int K, int Nout, int reluCols, int nRowB) {
    __shared__ __align__(16) char smem[33792];   // As 8K + Bs 8K | epi Lf 33.3K
    uint8_t* As = (uint8_t*)smem;             // [128][64] bytes
    uint8_t* Bs = (uint8_t*)(smem + 8192);
    const int bid = blockIdx.x;
    const int row0 = (bid % nRowB) * 128;
    const int col0 = (bid / nRowB) * 128;
    const int tid = threadIdx.x;
    const int wid = tid >> 6, lane = tid & 63;
    const int wm = wid & 1, wn = wid >> 1;
    const int l16 = lane & 15, l4 = lane >> 4;
    f32x4 acc[4][4] = {};

    // staging: 512 16B-units per matrix; unit v -> LDS byte v*16 (row=v>>2),
    // global 16B-chunk = (v&3) ^ ((row>>1)&3)
    int rl[2], gu[2];
    #pragma unroll
    for (int q = 0; q < 2; ++q) {
        const int v = wid * 64 + lane + 256 * q;
        rl[q] = v >> 2;
        gu[q] = (((v & 3) ^ ((rl[q] >> 1) & 3)) << 4);
    }
    char* AsB = smem + wid * 1024;
    char* BsB = smem + 8192 + wid * 1024;

    for (int k0 = 0; k0 < K; k0 += 64) {
        __syncthreads();
        #pragma unroll
        for (int q = 0; q < 2; ++q) {
            int ra = row0 + rl[q]; if (ra >= rows) ra = rows - 1;
            gload16(&A[(size_t)ra * K + k0 + gu[q]], AsB + q * 4096);
            gload16(&W[(size_t)(col0 + rl[q]) * K + k0 + gu[q]], BsB + q * 4096);
        }
        __syncthreads();
        #pragma unroll
        for (int s = 0; s < 2; ++s) {
            long long a[4], b[4];
            #pragma unroll
            for (int i = 0; i < 4; ++i) {
                const int ar = wm * 64 + i * 16 + l16;
                const int byt = ar * 64 + ((((s << 1) + (l4 >> 1)) ^ ((ar >> 1) & 3)) << 4) + (l4 & 1) * 8;
                a[i] = *(const long long*)&As[byt];
            }
            #pragma unroll
            for (int j = 0; j < 4; ++j) {
                const int br = wn * 64 + j * 16 + l16;
                const int byt = br * 64 + ((((s << 1) + (l4 >> 1)) ^ ((br >> 1) & 3)) << 4) + (l4 & 1) * 8;
                b[j] = *(const long long*)&Bs[byt];
            }
            #pragma unroll
            for (int i = 0; i < 4; ++i)
                #pragma unroll
                for (int j = 0; j < 4; ++j)
                    acc[i][j] = __builtin_amdgcn_mfma_f32_16x16x32_fp8_fp8(a[i], b[j], acc[i][j], 0, 0, 0);
        }
    }

    // epilogue: acc -> LDS f32 -> coalesced bf16 stores
    float* Lf = (float*)smem;               // [64][130]
    const int erow = tid >> 4;
    const int ecol = (tid & 15) * 8;
    const int gc = col0 + ecol;
    #pragma unroll
    for (int pass = 0; pass < 2; ++pass) {
        __syncthreads();
        if (wm == pass) {
            #pragma unroll
            for (int i = 0; i < 4; ++i)
                #pragma unroll
                for (int j = 0; j < 4; ++j) {
                    const int lc = wn * 64 + j * 16 + l16;
                    #pragma unroll
                    for (int r = 0; r < 4; ++r)
                        Lf[(i * 16 + l4 * 4 + r) * 130 + lc] = acc[i][j][r];
                }
        }
        __syncthreads();
        #pragma unroll
        for (int rr = 0; rr < 4; ++rr) {
            const int lrow = rr * 16 + erow;
            const int gr = row0 + pass * 64 + lrow;
            if (gr >= rows) continue;
            bf16x8 ob;
            #pragma unroll
            for (int c = 0; c < 8; ++c) {
                float t = Lf[lrow * 130 + ecol + c] * WSCI;
                if (EPI == 1) { if (gc + c < reluCols) t = fmaxf(t, 0.f); }
                else { t += bias[gc + c]; t = t / (1.f + __expf(-t)); }
                ob[c] = (__bf16)t;
            }
            *(bf16x8*)&outb[(size_t)gr * Nout + gc] = ob;
        }
    }
}

// ---------------- bf16 MFMA GEMM (m97-style) ----------------
// EPI 0: +bias -> bf16 ; EPI 3: resf+gate*(+bias) -> f32+bf16 (aproj)
// EPI 4: resf+(+bias) -> f32 (cproj) ; EPI 5: resf+gate*acc -> f32 (pw)
template<int EPI>
__global__ __launch_bounds__(256) void gemm_bt(
    const bf16* __restrict__ A, const bf16* __restrict__ W,
    const float* __restrict__ bias, const float* __restrict__ resf,
    const float* __restrict__ gate, int gateStride,
    bf16* __restrict__ outb, float* __restrict__ outf,
    int rows, int K, int Nout, int reluCols, int nRowB, int nColB) {
    __shared__ __align__(16) char smem[33792];
    bf16* As = (bf16*)smem;             // [128][64]
    bf16* Bs = (bf16*)(smem + 16384);   // [128][64]
    const int bid = blockIdx.x;
    int row_blk = bid % nRowB, col_blk = bid / nRowB;
    const int row0 = row_blk * 128;
    const int col0 = col_blk * 128;
    const int tid = threadIdx.x;
    const int wid = tid >> 6, lane = tid & 63;
    const int wm = wid & 1, wn = wid >> 1;
    const int l16 = lane & 15, l4 = lane >> 4;
    f32x4 acc[4][4] = {};

    const int sr = tid >> 3;
    const int kbsw = (((tid & 7) ^ (sr & 7)) << 3);
    int gra[4], gcl[4];
    #pragma unroll
    for (int p = 0; p < 4; ++p) {
        int r = row0 + p * 32 + sr; if (r >= rows) r = rows - 1;
        gra[p] = r;
        gcl[p] = col0 + p * 32 + sr;
    }
    char* AsB = smem + wid * 1024;
    char* BsB = smem + 16384 + wid * 1024;

    for (int k0 = 0; k0 < K; k0 += 64) {
        __syncthreads();
        #pragma unroll
        for (int p = 0; p < 4; ++p) {
            gload16(&A[(size_t)gra[p] * K + k0 + kbsw], AsB + p * 4096);
            gload16(&W[(size_t)gcl[p] * K + k0 + kbsw], BsB + p * 4096);
        }
        __syncthreads();
        #pragma unroll
        for (int kk = 0; kk < 2; ++kk) {
            bf16x8 a[4], b[4];
            #pragma unroll
            for (int i = 0; i < 4; ++i) {
                const int ar = wm * 64 + i * 16 + l16;
                a[i] = *(const bf16x8*)&As[ar * 64 + ((((kk << 2) + l4) ^ (ar & 7)) << 3)];
            }
            #pragma unroll
            for (int j = 0; j < 4; ++j) {
                const int br = wn * 64 + j * 16 + l16;
                b[j] = *(const bf16x8*)&Bs[br * 64 + ((((kk << 2) + l4) ^ (br & 7)) << 3)];
            }
            #pragma unroll
            for (int i = 0; i < 4; ++i)
                #pragma unroll
                for (int j = 0; j < 4; ++j)
                    acc[i][j] = __builtin_amdgcn_mfma_f32_16x16x32_bf16(a[i], b[j], acc[i][j], 0, 0, 0);
        }
    }

    float* Lf = (float*)smem;               // [64][130]
    const int erow = tid >> 4;
    const int ecol = (tid & 15) * 8;
    const int gc = col0 + ecol;
    #pragma unroll
    for (int pass = 0; pass < 2; ++pass) {
        __syncthreads();
        if (wm == pass) {
            #pragma unroll
            for (int i = 0; i < 4; ++i)
                #pragma unroll
                for (int j = 0; j < 4; ++j) {
                    const int lc = wn * 64 + j * 16 + l16;
                    #pragma unroll
                    for (int r = 0; r < 4; ++r)
                        Lf[(i * 16 + l4 * 4 + r) * 130 + lc] = acc[i][j][r];
                }
        }
        __syncthreads();
        #pragma unroll
        for (int rr = 0; rr < 4; ++rr) {
            const int lrow = rr * 16 + erow;
            const int gr = row0 + pass * 64 + lrow;
            if (gr >= rows) continue;
            float v[8];
            #pragma unroll
            for (int c = 0; c < 8; ++c) v[c] = Lf[lrow * 130 + ecol + c];
            const size_t oi0 = (size_t)gr * Nout + gc;
            if (EPI == 0) {
                bf16x8 ob;
                #pragma unroll
                for (int c = 0; c < 8; ++c) ob[c] = (__bf16)(v[c] + bias[gc + c]);
                *(bf16x8*)&outb[oi0] = ob;
            } else if (EPI == 3) {
                const float* gp = &gate[(gr >> 12) * gateStride + gc];
                const float* rp = &resf[oi0];
                f32x4 o0, o1; bf16x8 ob;
                #pragma unroll
                for (int c = 0; c < 8; ++c) {
                    float t = v[c] + bias[gc + c];
                    t = rp[c] + gp[c] * t;
                    if (c < 4) o0[c] = t; else o1[c - 4] = t;
                    ob[c] = (__bf16)t;
                }
                *(f32x4*)&outf[oi0] = o0;
                *(f32x4*)&outf[oi0 + 4] = o1;
                *(bf16x8*)&outb[oi0] = ob;
            } else if (EPI == 4) {
                const float* rp = &resf[oi0];
                f32x4 o0, o1;
                #pragma unroll
                for (int c = 0; c < 8; ++c) {
                    float t = rp[c] + v[c] + bias[gc + c];
                    if (c < 4) o0[c] = t; else o1[c - 4] = t;
                }
                *(f32x4*)&outf[oi0] = o0;
                *(f32x4*)&outf[oi0 + 4] = o1;
            } else {   // EPI 5
                const float* gp = &gate[(gr >> 12) * gateStride + gc];
                const float* rp = &resf[oi0];
                f32x4 o0, o1;
                #pragma unroll
                for (int c = 0; c < 8; ++c) {
                    float t = rp[c] + gp[c] * v[c];
                    if (c < 4) o0[c] = t; else o1[c - 4] = t;
                }
                *(f32x4*)&outf[oi0] = o0;
                *(f32x4*)&outf[oi0 + 4] = o1;
            }
        }
    }
}

// ---------------- LiteLA: vk = [v;1] @ k^T over n, per (b,h) ----------------
__global__ __launch_bounds__(256) void lite_vk(
    const bf16* __restrict__ qkv, float* __restrict__ vk) {
    const int b = blockIdx.x / 36, h = blockIdx.x % 36;
    const int n0 = blockIdx.y * 256;
    __shared__ bf16 ksm[64 * 32];
    __shared__ bf16 vsm[64 * 32];
    const int t = threadIdx.x;
    const int ev = t >> 3, kq = (t & 7) * 4;
    float a0 = 0, a1 = 0, a2 = 0, a3 = 0;
    float q0 = 0, q1 = 0, q2 = 0, q3 = 0;
    for (int tile = 0; tile < 4; ++tile) {
        const int nb = n0 + tile * 64;
        __syncthreads();
        {
            const int nl = t >> 2, part = (t & 3) * 8;
            const size_t rbase = ((size_t)b * NTOK + nb + nl) * (3 * CD);
            *(bf16x8*)&ksm[nl * 32 + part] = *(const bf16x8*)&qkv[rbase + CD     + h * 32 + part];
            *(bf16x8*)&vsm[nl * 32 + part] = *(const bf16x8*)&qkv[rbase + 2 * CD + h * 32 + part];
        }
        __syncthreads();
        #pragma unroll 4
        for (int nl = 0; nl < 64; ++nl) {
            const float vv = b2f(vsm[nl * 32 + ev]);
            const float k0 = b2f(ksm[nl * 32 + kq + 0]);
            const float k1 = b2f(ksm[nl * 32 + kq + 1]);
            const float k2 = b2f(ksm[nl * 32 + kq + 2]);
            const float k3 = b2f(ksm[nl * 32 + kq + 3]);
            a0 += vv * k0; a1 += vv * k1; a2 += vv * k2; a3 += vv * k3;
            if (ev == 0) { q0 += k0; q1 += k1; q2 += k2; q3 += k3; }
        }
    }
    float* dst = &vk[(((size_t)b * 36 + h) * 33 + ev) * 32 + kq];
    atomicAdd(dst + 0, a0); atomicAdd(dst + 1, a1);
    atomicAdd(dst + 2, a2); atomicAdd(dst + 3, a3);
    if (ev == 0) {
        float* d2 = &vk[(((size_t)b * 36 + h) * 33 + 32) * 32 + kq];
        atomicAdd(d2 + 0, q0); atomicAdd(d2 + 1, q1);
        atomicAdd(d2 + 2, q2); atomicAdd(d2 + 3, q3);
    }
}

// u[b,n,h*32+d] = (vk[d,:] . q) / (vk[32,:] . q + eps)
__global__ __launch_bounds__(256) void lite_out(
    const bf16* __restrict__ qkv, const float* __restrict__ vk,
    bf16* __restrict__ u) {
    const int b = blockIdx.x / 36, h = blockIdx.x % 36;
    const int n = blockIdx.y * 256 + threadIdx.x;
    __shared__ float vks[33 * 32];
    const float* src = &vk[((size_t)b * 36 + h) * 33 * 32];
    for (int i = threadIdx.x; i < 33 * 32; i += 256) vks[i] = src[i];
    __syncthreads();
    float q[32];
    const bf16x8* qv = (const bf16x8*)&qkv[((size_t)b * NTOK + n) * (3 * CD) + h * 32];
    #pragma unroll
    for (int w = 0; w < 4; ++w) {
        bf16x8 qq = qv[w];
        #pragma unroll
        for (int e = 0; e < 8; ++e) q[w * 8 + e] = (float)qq[e];
    }
    float denom = 0.f;
    #pragma unroll
    for (int e = 0; e < 32; ++e) denom += vks[32 * 32 + e] * q[e];
    const float rd = 1.f / (denom + 1e-8f);
    bf16* up = &u[((size_t)b * NTOK + n) * CD + h * 32];
    #pragma unroll 1
    for (int d = 0; d < 32; ++d) {
        float acc = 0.f;
        #pragma unroll
        for (int e = 0; e < 32; ++e) acc += vks[d * 32 + e] * q[e];
        up[d] = f2b(acc * rd);
    }
}

// ---------------- cross attention prep: K zero-pad + V transpose ----------------
__global__ __launch_bounds__(256) void prep_attn(
    const bf16* __restrict__ kvb, bf16* __restrict__ Kp, bf16* __restrict__ VtG) {
    const int b = blockIdx.x >> 4, h = blockIdx.x & 15;
    const int tid = threadIdx.x;
    bf16* kp = Kp + (size_t)blockIdx.x * (320 * 72);
    bf16* vt = VtG + (size_t)blockIdx.x * (80 * 328);
    const bf16x8 z = bz8();
    for (int i = tid; i < 320 * 9; i += 256) {
        const int m = i / 9, part = (i % 9) * 8;
        bf16x8 v = z;
        if (m < MTOK)
            v = *(const bf16x8*)&kvb[((size_t)b * MTOK + m) * (2 * CD) + h * 72 + part];
        *(bf16x8*)&kp[m * 72 + part] = v;
    }
    for (int i = tid; i < 80 * 328; i += 256) {
        const int d = i / 328, mm = i - d * 328;
        bf16 v = f2b(0.f);
        if (mm < MTOK && d < 72)
            v = kvb[((size_t)b * MTOK + mm) * (2 * CD) + CD + h * 72 + d];
        vt[i] = v;
    }
}

// ---------------- cross attention: MFMA flash, 64 Q-rows per block ----------------
__global__ __launch_bounds__(256) void cross_attn_mfma(
    const bf16* __restrict__ qx, const bf16* __restrict__ Kp,
    const bf16* __restrict__ VtG, bf16* __restrict__ attn) {
    const int bh = blockIdx.x;
    const int b = bh >> 4;
    const int row0 = blockIdx.y * 64;
    __shared__ bf16 Ks[320 * 72];
    __shared__ bf16 Vt[80 * 328];
    __shared__ bf16 Ps[64 * 328];
    const int tid = threadIdx.x;
    const int wid = tid >> 6, lane = tid & 63;
    const int l16 = lane & 15, l4 = lane >> 4;
    const bf16 zb = f2b(0.f);
    const bf16x8 zv8 = bz8();

    {
        const bf16x8* Kg = (const bf16x8*)(Kp + (size_t)bh * (320 * 72));
        bf16x8* Kl = (bf16x8*)Ks;
        for (int i = tid; i < 2880; i += 256) Kl[i] = Kg[i];
        const bf16x8* Vg = (const bf16x8*)(VtG + (size_t)bh * (80 * 328));
        bf16x8* Vl = (bf16x8*)Vt;
        for (int i = tid; i < 3280; i += 256) Vl[i] = Vg[i];
    }
    for (int i = lane; i < 16 * 16; i += 64)
        Ps[(wid * 16 + (i >> 4)) * 328 + 304 + (i & 15)] = zb;

    bf16x8 aq[3];
    {
        const int qrow = row0 + wid * 16 + l16;
        const bf16* qp = &qx[((size_t)b * NTOK + qrow) * CD + (bh & 15) * 72];
        aq[0] = *(const bf16x8*)&qp[l4 * 8];
        aq[1] = *(const bf16x8*)&qp[32 + l4 * 8];
        aq[2] = (l4 == 0) ? *(const bf16x8*)&qp[64] : zv8;
    }
    __syncthreads();

    f32x4 sa[19] = {};
    #pragma unroll
    for (int t = 0; t < 19; ++t) {
        const bf16* kr = &Ks[(t * 16 + l16) * 72];
        bf16x8 b0 = *(const bf16x8*)&kr[l4 * 8];
        bf16x8 b1 = *(const bf16x8*)&kr[32 + l4 * 8];
        bf16x8 b2 = (l4 == 0) ? *(const bf16x8*)&kr[64] : zv8;
        sa[t] = __builtin_amdgcn_mfma_f32_16x16x32_bf16(aq[0], b0, sa[t], 0, 0, 0);
        sa[t] = __builtin_amdgcn_mfma_f32_16x16x32_bf16(aq[1], b1, sa[t], 0, 0, 0);
        sa[t] = __builtin_amdgcn_mfma_f32_16x16x32_bf16(aq[2], b2, sa[t], 0, 0, 0);
    }

    const float scale = 0.11785113019775792f;   // 1/sqrt(72)
    if (l16 >= 12) { sa[18][0] = sa[18][1] = sa[18][2] = sa[18][3] = -3.0e37f; }
    float mr[4] = {-3.0e38f, -3.0e38f, -3.0e38f, -3.0e38f};
    #pragma unroll
    for (int t = 0; t < 19; ++t)
        #pragma unroll
        for (int r = 0; r < 4; ++r) {
            const float s = sa[t][r] * scale;
            sa[t][r] = s;
            mr[r] = fmaxf(mr[r], s);
        }
    #pragma unroll
    for (int off = 1; off < 16; off <<= 1)
        #pragma unroll
        for (int r = 0; r < 4; ++r)
            mr[r] = fmaxf(mr[r], __shfl_xor(mr[r], off, 64));
    float lr[4] = {0.f, 0.f, 0.f, 0.f};
    #pragma unroll
    for (int t = 0; t < 19; ++t)
        #pragma unroll
        for (int r = 0; r < 4; ++r) {
            const float p = __expf(sa[t][r] - mr[r]);
            lr[r] += p;
            Ps[(wid * 16 + l4 * 4 + r) * 328 + t * 16 + l16] = f2b(p);
        }
    #pragma unroll
    for (int off = 1; off < 16; off <<= 1)
        #pragma unroll
        for (int r = 0; r < 4; ++r)
            lr[r] += __shfl_xor(lr[r], off, 64);
    __syncthreads();

    f32x4 oa[5] = {};
    #pragma unroll
    for (int kc = 0; kc < 10; ++kc) {
        bf16x8 pa = *(const bf16x8*)&Ps[(wid * 16 + l16) * 328 + kc * 32 + l4 * 8];
        #pragma unroll
        for (int dt = 0; dt < 5; ++dt) {
            bf16x8 vb = *(const bf16x8*)&Vt[(dt * 16 + l16) * 328 + kc * 32 + l4 * 8];
            oa[dt] = __builtin_amdgcn_mfma_f32_16x16x32_bf16(pa, vb, oa[dt], 0, 0, 0);
        }
    }
    #pragma unroll
    for (int r = 0; r < 4; ++r) {
        const float rinv = 1.f / lr[r];
        const int gr = row0 + wid * 16 + l4 * 4 + r;
        bf16* op = &attn[((size_t)b * NTOK + gr) * CD + (bh & 15) * 72];
        #pragma unroll
        for (int dt = 0; dt < 5; ++dt) {
            const int d = dt * 16 + l16;
            if (d < 72) op[d] = f2b(oa[dt][r] * rinv);
        }
    }
}

// ---------------- depthwise 3x3 conv + GLU (8 ch/thread, 16B loads) ----------------
__global__ __launch_bounds__(128) void dwconv_glu2(
    const bf16* __restrict__ hbuf, const bf16* __restrict__ wt,
    const float* __restrict__ dwb, bf16* __restrict__ glu) {
    const int cg = blockIdx.y * 128 + threadIdx.x;
    if (cg >= 360) return;
    const int c0 = cg * 8;
    const int n = blockIdx.x & 4095;
    const int b = blockIdx.x >> 12;
    const int y0 = n >> 6, x0 = n & 63;
    float a[8], g[8];
    #pragma unroll
    for (int j = 0; j < 8; ++j) { a[j] = dwb[c0 + j]; g[j] = dwb[HIDD + c0 + j]; }
    #pragma unroll
    for (int dy = -1; dy <= 1; ++dy) {
        const int yy = y0 + dy;
        if (yy < 0 || yy >= 64) continue;
        #pragma unroll
        for (int dx = -1; dx <= 1; ++dx) {
            const int xx = x0 + dx;
            if (xx < 0 || xx >= 64) continue;
            const int k = (dy + 1) * 3 + (dx + 1);
            const size_t base = ((size_t)b * NTOK + yy * 64 + xx) * HID2;
            const bf16x8 va = *(const bf16x8*)&hbuf[base + c0];
            const bf16x8 vg = *(const bf16x8*)&hbuf[base + HIDD + c0];
            const bf16x8 wa = *(const bf16x8*)&wt[k * HID2 + c0];
            const bf16x8 wg = *(const bf16x8*)&wt[k * HID2 + HIDD + c0];
            #pragma unroll
            for (int j = 0; j < 8; ++j) {
                a[j] += (float)wa[j] * (float)va[j];
                g[j] += (float)wg[j] * (float)vg[j];
            }
        }
    }
    bf16x8 o;
    #pragma unroll
    for (int j = 0; j < 8; ++j) {
        const float s = g[j] / (1.f + __expf(-g[j]));
        o[j] = (__bf16)(a[j] * s);
    }
    *(bf16x8*)&glu[((size_t)b * NTOK + n) * HIDD + c0] = o;
}

// ---------------- launcher ----------------
extern "C" void kernel_launch(void* const* d_in, const int* in_sizes, int n_in,
                              void* d_out, int out_size, void* d_ws, size_t ws_size,
                              hipStream_t stream) {
    (void)in_sizes; (void)n_in; (void)out_size; (void)ws_size;
    const float* x       = (const float*)d_in[0];
    const float* y       = (const float*)d_in[1];
    const float* t       = (const float*)d_in[2];
    const float* sst     = (const float*)d_in[3];
    const float* qkv_w   = (const float*)d_in[4];
    const float* aproj_w = (const float*)d_in[5];
    const float* aproj_b = (const float*)d_in[6];
    const float* q_w     = (const float*)d_in[7];
    const float* q_b     = (const float*)d_in[8];
    const float* kv_w    = (const float*)d_in[9];
    const float* kv_b    = (const float*)d_in[10];
    const float* cproj_w = (const float*)d_in[11];
    const float* cproj_b = (const float*)d_in[12];
    const float* inv_w   = (const float*)d_in[13];
    const float* inv_b   = (const float*)d_in[14];
    const float* dw_w    = (const float*)d_in[15];
    const float* dw_b    = (const float*)d_in[16];
    const float* pw_w    = (const float*)d_in[17];
    float* out = (float*)d_out;

    char* ws = (char*)d_ws;
    size_t cur = 0;
    auto take = [&](size_t bytes) -> char* {
        char* p = ws + cur;
        cur = (cur + bytes + 255) & ~(size_t)255;
        return p;
    };
    float* mbuf   = (float*)take(BSZ * 6 * CD * 4);
    float* vkbuf  = (float*)take(BSZ * 36 * 33 * 32 * 4);
    uint8_t* wqkv = (uint8_t*)take((size_t)3 * CD * CD);    // fp8
    bf16* waproj  = (bf16*)take((size_t)CD * CD * 2);
    bf16* wq      = (bf16*)take((size_t)CD * CD * 2);
    bf16* wkv     = (bf16*)take((size_t)2 * CD * CD * 2);
    bf16* wcproj  = (bf16*)take((size_t)CD * CD * 2);
    uint8_t* winv = (uint8_t*)take((size_t)HID2 * CD);      // fp8
    bf16* wpw     = (bf16*)take((size_t)CD * HIDD * 2);
    bf16* wtdw    = (bf16*)take((size_t)9 * HID2 * 2);
    bf16* yb      = (bf16*)take((size_t)KVROWS * CD * 2);
    bf16* kvbuf   = (bf16*)take((size_t)KVROWS * 2 * CD * 2);
    bf16* Kp      = (bf16*)take((size_t)32 * 320 * 72 * 2);
    bf16* VtG     = (bf16*)take((size_t)32 * 80 * 328 * 2);
    bf16* P       = (bf16*)take((size_t)ROWS * HID2 * 2);   // qkv, later h
    bf16* Q       = (bf16*)take((size_t)ROWS * HIDD * 2);   // u, later glu
    bf16* R       = (bf16*)take((size_t)ROWS * CD * 2);     // x1f8 / xa_bf / attn
    bf16* S       = (bf16*)take((size_t)ROWS * CD * 2);     // qx / x2f8
    float* xa_f   = (float*)take((size_t)ROWS * CD * 4);

    bf16* qkvb = P;  bf16* hbuf = P;
    bf16* ubuf = Q;  bf16* glub = Q;
    bf16* xa_bf = R, *attnb = R;
    uint8_t* x1f8 = (uint8_t*)R;    // dead before xa_bf is written
    bf16* qx = S;
    uint8_t* x2f8 = (uint8_t*)S;    // qx dead before x2f8 is written
    float* xb_f = out;  // d_out doubles as the f32 xb buffer

    prep_all<<<(PB10 + 255) / 256, 256, 0, stream>>>(
        qkv_w, aproj_w, q_w, kv_w, cproj_w, inv_w, pw_w, y, sst, t, dw_w,
        wqkv, waproj, wq, wkv, wcproj, winv, wpw, yb, mbuf, wtdw, vkbuf);

    // --- LiteLA branch ---
    ln_mod8<<<ROWS, 256, 0, stream>>>(x, mbuf, 0, 1, x1f8);
    gemm_f8<1><<<64 * 27, 256, 0, stream>>>(x1f8, wqkv, nullptr, qkvb,
                                            ROWS, CD, 3 * CD, 2 * CD, 64);
    lite_vk<<<dim3(72, 16), 256, 0, stream>>>(qkvb, vkbuf);
    lite_out<<<dim3(72, 16), 256, 0, stream>>>(qkvb, vkbuf, ubuf);
    gemm_bt<3><<<64 * 9, 256, 0, stream>>>(ubuf, waproj, aproj_b, x, mbuf + 2 * CD, 6 * CD,
                                           xa_bf, xa_f, ROWS, CD, CD, 0, 64, 9);

    // --- cross attention branch ---
    gemm_bt<0><<<64 * 9, 256, 0, stream>>>(xa_bf, wq, q_b, nullptr, nullptr, 0,
                                           qx, nullptr, ROWS, CD, CD, 0, 64, 9);
    gemm_bt<0><<<5 * 18, 256, 0, stream>>>(yb, wkv, kv_b, nullptr, nullptr, 0,
                                           kvbuf, nullptr, KVROWS, CD, 2 * CD, 0, 5, 18);
    prep_attn<<<32, 256, 0, stream>>>(kvbuf, Kp, VtG);
    cross_attn_mfma<<<dim3(32, 64), 256, 0, stream>>>(qx, Kp, VtG, attnb);
    gemm_bt<4><<<64 * 9, 256, 0, stream>>>(attnb, wcproj, cproj_b, xa_f, nullptr, 0,
                                           nullptr, xb_f, ROWS, CD, CD, 0, 64, 9);

    // --- GLUMBConv branch ---
    ln_mod8<<<ROWS, 256, 0, stream>>>(xb_f, mbuf, 3, 4, x2f8);
    gemm_f8<2><<<64 * 45, 256, 0, stream>>>(x2f8, winv, inv_b, hbuf,
                                            ROWS, CD, HID2, 0, 64);
    dwconv_glu2<<<dim3(ROWS, 3), 128, 0, stream>>>(hbuf, wtdw, dw_b, glub);
    gemm_bt<5><<<64 * 9, 256, 0, stream>>>(glub, wpw, nullptr, xb_f, mbuf + 5 * CD, 6 * CD,
                                           nullptr, out, ROWS, HIDD, CD, 0, 64, 9);
}